// Round 9
// baseline (270.977 us; speedup 1.0000x reference)
//
#include <hip/hip_runtime.h>
#include <math.h>

#define N_ 16
#define C_ 512
#define L_ 3000
#define A_ 128
#define LT_ 48     // l-tiles of 64

typedef _Float16 f16;
typedef __attribute__((ext_vector_type(8))) _Float16 f16x8;
typedef __attribute__((ext_vector_type(4))) _Float16 f16x4;
typedef __attribute__((ext_vector_type(4))) float f32x4;

// ---------------------------------------------------------------------------
// K1: masked mean per (n,c); "std" = sqrt(clip(mean - mean^2)) (faithful to ref:
// var_like = sum(m*(x - mean^2)) = mean - mean^2 since weights sum to 1)
// [proven R6]
// ---------------------------------------------------------------------------
__global__ __launch_bounds__(256) void k_stats(const float* __restrict__ x,
                                               const float* __restrict__ lengths,
                                               float* __restrict__ mg,
                                               float* __restrict__ sg) {
  int n = blockIdx.x >> 9;
  float thr = lengths[n] * (float)L_;
  int T = (int)ceilf(thr); if (T > L_) T = L_;
  const float4* row = (const float4*)(x + (size_t)blockIdx.x * L_);
  int tid = threadIdx.x;
  float sum = 0.f;
  int nf4 = (T + 3) >> 2;
  for (int i = tid; i < nf4; i += 256) {
    float4 v = row[i];
    int l = i * 4;
    if (l + 4 <= T) sum += (v.x + v.y) + (v.z + v.w);
    else {
      if (l     < T) sum += v.x;
      if (l + 1 < T) sum += v.y;
      if (l + 2 < T) sum += v.z;
      if (l + 3 < T) sum += v.w;
    }
  }
  #pragma unroll
  for (int off = 32; off; off >>= 1) sum += __shfl_down(sum, off, 64);
  __shared__ float red[4];
  int wv = tid >> 6, ln = tid & 63;
  if (ln == 0) red[wv] = sum;
  __syncthreads();
  if (tid == 0) {
    float tot = red[0] + red[1] + red[2] + red[3];
    float mean = tot / (float)T;
    mg[blockIdx.x] = mean;
    sg[blockIdx.x] = sqrtf(fmaxf(mean - mean * mean, 1e-12f));
  }
}

// ---------------------------------------------------------------------------
// K1b: per-(n,a) bias d = W1m@mean_g + W1s@std_g + b1 ; BN fold;
//      cast W1x -> W1h [128][512] f16, W2 -> W2h [512][128] f16  [proven R6]
// ---------------------------------------------------------------------------
__global__ __launch_bounds__(256) void k_prep(const float* __restrict__ W1,
    const float* __restrict__ b1, const float* __restrict__ gamma,
    const float* __restrict__ beta, const float* __restrict__ bmean,
    const float* __restrict__ bvar, const float* __restrict__ W2,
    const float* __restrict__ mg, const float* __restrict__ sg,
    float* __restrict__ dba, float* __restrict__ scale, float* __restrict__ shift,
    f16* __restrict__ W1h, f16* __restrict__ W2h) {
  int n = blockIdx.x;
  __shared__ float sm[C_], ss[C_];
  int tid = threadIdx.x;
  for (int c = tid; c < C_; c += 256) { sm[c] = mg[n * C_ + c]; ss[c] = sg[n * C_ + c]; }
  __syncthreads();
  int wv = tid >> 6, ln = tid & 63;
  for (int a = wv; a < A_; a += 4) {
    const float* wm = W1 + (size_t)a * (3 * C_) + C_;   // mean cols, then std cols
    float acc = 0.f;
    for (int c = ln; c < C_; c += 64) acc += wm[c] * sm[c] + wm[C_ + c] * ss[c];
    #pragma unroll
    for (int off = 32; off; off >>= 1) acc += __shfl_down(acc, off, 64);
    if (ln == 0) dba[n * A_ + a] = acc + b1[a];
  }
  int base = n * 4096;
  for (int i = tid; i < 4096; i += 256) {
    int idx = base + i;
    int a = idx >> 9, c = idx & 511;
    W1h[idx] = (f16)W1[(size_t)a * (3 * C_) + c];  // x-columns only
    W2h[idx] = (f16)W2[idx];                       // [512][128] contiguous
  }
  if (n == 0 && tid < A_) {
    float sc = gamma[tid] * rsqrtf(bvar[tid] + 1e-5f);
    scale[tid] = sc;
    shift[tid] = beta[tid] - bmean[tid] * sc;
  }
}

// ---------------------------------------------------------------------------
// k_mega: per (lt, n) 64-l tile, everything fused, no HBM intermediates:
//   phase 1: stage x^T (fp32 LDS transpose -> f16), GEMM1 W1h@x^T (K=512)
//   phase 2: activated h tile -> LDS (hts, [64 l][136] f16)
//   phase 3: GEMM2 W2h@hts^T over all 512 c (8 mi2 x 16 c per wave),
//            per-mi2 sw LDS score round-trip, masked softmax partials (m,s,t)
// grid (48 lt, 16 n) = 768 blocks; 256 thr = 4 waves.
// LDS: staging {xf32[32][72] 9216 | xts[64][40] 5120 | w1s[128][40] 10240}
//      = 24576 B; hts[64][136]=17408 B overlaps staging (dead by then);
//      sw 4x[16][72] f16 = 9216 B at 24576. Total 33792 B -> 4 blocks/CU cap.
// Known ineff (audited, accepted): 4-way bank conflict on the xf32
// transpose-read (bank independent of c-chunk; pitch-73 would fix banks but
// break float4 staging alignment). Revisit only if counters say so.
// ---------------------------------------------------------------------------
__global__ __launch_bounds__(256) void k_mega(const float* __restrict__ x,
    const f16* __restrict__ W1h, const f16* __restrict__ W2h,
    const float* __restrict__ dba, const float* __restrict__ scale,
    const float* __restrict__ shift, const float* __restrict__ b2,
    const float* __restrict__ lengths,
    float* __restrict__ pm, float* __restrict__ ps, float* __restrict__ pt) {
  int lt = blockIdx.x, n = blockIdx.y;
  int lt0 = lt * 64;
  float thr = lengths[n] * (float)L_;
  int T = (int)ceilf(thr); if (T > L_) T = L_;
  int tid = threadIdx.x;

  if (lt0 >= T) {            // fully masked tile: neutral partials, done
    for (int c = tid; c < C_; c += 256) {
      size_t idx = ((size_t)n * LT_ + lt) * C_ + c;
      pm[idx] = -1e30f; ps[idx] = 0.f; pt[idx] = 0.f;
    }
    return;
  }

  __shared__ __align__(16) char smem[33792];
  float* xf32 = (float*)smem;                 // [32][72] fp32
  f16* xts = (f16*)(smem + 9216);             // [64][40] f16 (x^T tile)
  f16* w1s = (f16*)(smem + 14336);            // [128][40] f16
  f16* hts = (f16*)smem;                      // [64][136] f16 (phase 2+, overlaps)
  int wid = tid >> 6, lane = tid & 63;
  int fr = lane & 15, fq = lane >> 4;
  f16* sw = (f16*)(smem + 24576) + wid * (16 * 72);  // per-wave [16][72] f16

  // ---- phase 1: GEMM1, acc[a 4][l 2] per wave (2x2 wave layout) ----
  int wr = wid >> 1, wc = wid & 1;
  f32x4 acc[4][2];
  #pragma unroll
  for (int mi = 0; mi < 4; ++mi)
    #pragma unroll
    for (int ni = 0; ni < 2; ++ni) { f32x4 z = {0.f,0.f,0.f,0.f}; acc[mi][ni] = z; }

  int s_c  = tid >> 4;            // 0..15 (c row)
  int s_l4 = (tid & 15) * 4;      // 0..60 (l within tile)
  int t_l  = tid >> 2;            // 0..63 (transpose-read l row)
  int t_c8 = (tid & 3) * 8;       // 0/8/16/24 (c chunk)
  int w_r  = tid >> 1;            // 0..127 (W1 row)
  int w_h  = (tid & 1) * 16;      // 0/16 (c chunk)
  const float* xn = x + (size_t)n * C_ * L_;

  for (int c0 = 0; c0 < C_; c0 += 32) {
    __syncthreads();   // prev xts/w1s consumed, prev xf32 transposed
    { // stage w1s [128 a][32 c]
      const f16* srcw = W1h + (size_t)w_r * C_ + c0 + w_h;
      *(f16x8*)&w1s[w_r * 40 + w_h]     = *(const f16x8*)srcw;
      *(f16x8*)&w1s[w_r * 40 + w_h + 8] = *(const f16x8*)(srcw + 8);
    }
    { // stage xf32 [32 c][64 l] (coalesced float4 along l; L_%4==0 no straddle)
      #pragma unroll
      for (int p = 0; p < 2; ++p) {
        int c = s_c + p * 16;
        int l = lt0 + s_l4;
        float4 v = make_float4(0.f, 0.f, 0.f, 0.f);
        if (l < L_) v = *(const float4*)(xn + (size_t)(c0 + c) * L_ + l);
        *(float4*)&xf32[c * 72 + s_l4] = v;
      }
    }
    __syncthreads();   // xf32 ready
    { // transpose-read -> xts [64 l][32 c] f16
      f16x8 o;
      #pragma unroll
      for (int j = 0; j < 8; ++j) o[j] = (f16)xf32[(t_c8 + j) * 72 + t_l];
      *(f16x8*)&xts[t_l * 40 + t_c8] = o;
    }
    __syncthreads();   // xts + w1s ready
    // MFMA, K=32 per step
    f16x8 af[4];
    #pragma unroll
    for (int mi = 0; mi < 4; ++mi)
      af[mi] = *(const f16x8*)&w1s[(wr * 64 + mi * 16 + fr) * 40 + fq * 8];
    #pragma unroll
    for (int ni = 0; ni < 2; ++ni) {
      f16x8 bf = *(const f16x8*)&xts[(wc * 32 + ni * 16 + fr) * 40 + fq * 8];
      #pragma unroll
      for (int mi = 0; mi < 4; ++mi)
        acc[mi][ni] = __builtin_amdgcn_mfma_f32_16x16x32_f16(af[mi], bf, acc[mi][ni], 0, 0, 0);
    }
  }
  __syncthreads();   // all MFMA reads of staging done -> hts region writable

  // ---- phase 2: activated h tile -> hts LDS ----
  // D layout: col(lane&15)=l, row((lane>>4)*4+reg)=a  [proven]
  #pragma unroll
  for (int mi = 0; mi < 4; ++mi) {
    int a0 = wr * 64 + mi * 16 + fq * 4;
    f32x4 dbv = *(const f32x4*)(dba + n * A_ + a0);
    f32x4 scv = *(const f32x4*)(scale + a0);
    f32x4 shv = *(const f32x4*)(shift + a0);
    #pragma unroll
    for (int ni = 0; ni < 2; ++ni) {
      int ll = wc * 32 + ni * 16 + fr;
      f16x4 pack;
      #pragma unroll
      for (int r = 0; r < 4; ++r) {
        float v = acc[mi][ni][r] + dbv[r];
        v = fmaxf(v, 0.f) * scv[r] + shv[r];
        pack[r] = (f16)tanhf(v);
      }
      *(f16x4*)&hts[ll * 136 + a0] = pack;
    }
  }
  __syncthreads();   // hts ready for all waves

  // ---- phase 3: GEMM2 + masked softmax partials, 16 c per wave per mi2 ----
  int cw = wid * 128;
  #pragma unroll 1
  for (int mi2 = 0; mi2 < 8; ++mi2) {
    int cm = cw + mi2 * 16;
    f16x8 af2[4];
    #pragma unroll
    for (int kk = 0; kk < 4; ++kk)
      af2[kk] = *(const f16x8*)(W2h + (size_t)(cm + fr) * A_ + kk * 32 + fq * 8);
    f32x4 sacc[4];
    #pragma unroll
    for (int ni = 0; ni < 4; ++ni) {
      f32x4 z = {0.f, 0.f, 0.f, 0.f};
      sacc[ni] = z;
      #pragma unroll
      for (int kk = 0; kk < 4; ++kk)
        sacc[ni] = __builtin_amdgcn_mfma_f32_16x16x32_f16(af2[kk],
            *(const f16x8*)&hts[(size_t)(ni * 16 + fr) * 136 + kk * 32 + fq * 8],
            sacc[ni], 0, 0, 0);
    }
    int cme = cm + fq * 4;
    f32x4 b2v = *(const f32x4*)(b2 + cme);
    #pragma unroll
    for (int ni = 0; ni < 4; ++ni)
      #pragma unroll
      for (int r = 0; r < 4; ++r)
        sw[(fq * 4 + r) * 72 + ni * 16 + fr] = (f16)(sacc[ni][r] + b2v[r]);
    __syncthreads();   // sw visible (cross-lane transpose)
    // pass 2: lane owns 4 consecutive l for its 4 c rows
    #pragma unroll
    for (int r = 0; r < 4; ++r) {
      f16x4 svh = *(const f16x4*)&sw[(fq * 4 + r) * 72 + fr * 4];
      int lb = lt0 + fr * 4;
      const float* xr = x + ((size_t)n * C_ + cme + r) * L_;
      float4 xv = (lb < L_) ? *(const float4*)(xr + lb) : make_float4(0.f,0.f,0.f,0.f);
      float sc[4] = {(float)svh[0], (float)svh[1], (float)svh[2], (float)svh[3]};
      float xvv[4] = {xv.x, xv.y, xv.z, xv.w};
      float mloc = -1e30f;
      #pragma unroll
      for (int j = 0; j < 4; ++j) if (lb + j < T) mloc = fmaxf(mloc, sc[j]);
      float sloc = 0.f, tloc = 0.f;
      #pragma unroll
      for (int j = 0; j < 4; ++j) {
        if (lb + j < T) {
          float w = __expf(sc[j] - mloc);
          sloc += w;
          tloc += w * xvv[j];
        }
      }
      #pragma unroll
      for (int off = 8; off; off >>= 1) {
        float om = __shfl_xor(mloc, off, 64);
        float os = __shfl_xor(sloc, off, 64);
        float ot = __shfl_xor(tloc, off, 64);
        float mn = fmaxf(mloc, om);
        float e1 = __expf(mloc - mn), e2 = __expf(om - mn);
        sloc = sloc * e1 + os * e2;
        tloc = tloc * e1 + ot * e2;
        mloc = mn;
      }
      if (fr == 0) {
        size_t idx = ((size_t)n * LT_ + lt) * C_ + cme + r;
        pm[idx] = mloc; ps[idx] = sloc; pt[idx] = tloc;
      }
    }
    __syncthreads();   // protect sw reads before next mi2 overwrites
  }
}

// ---------------------------------------------------------------------------
// k_comb: combine the 48 l-tile partials, emit mean and std
// ---------------------------------------------------------------------------
__global__ __launch_bounds__(256) void k_comb(const float* __restrict__ pm,
    const float* __restrict__ ps, const float* __restrict__ pt,
    float* __restrict__ out) {
  int idx = blockIdx.x * 256 + threadIdx.x;
  if (idx >= N_ * C_) return;
  int n = idx >> 9, c = idx & 511;
  float mn = -1e30f;
  for (int g = 0; g < LT_; ++g) mn = fmaxf(mn, pm[((size_t)n * LT_ + g) * C_ + c]);
  float S = 0.f, Tt = 0.f;
  for (int g = 0; g < LT_; ++g) {
    size_t i = ((size_t)n * LT_ + g) * C_ + c;
    float e = __expf(pm[i] - mn);
    S  += ps[i] * e;
    Tt += pt[i] * e;
  }
  float mean = Tt / S;
  out[n * 1024 + c]       = mean;
  out[n * 1024 + 512 + c] = sqrtf(fmaxf(mean - mean * mean, 1e-12f));
}

// ---------------------------------------------------------------------------
extern "C" void kernel_launch(void* const* d_in, const int* in_sizes, int n_in,
                              void* d_out, int out_size, void* d_ws, size_t ws_size,
                              hipStream_t stream) {
  const float* x       = (const float*)d_in[0];
  const float* lengths = (const float*)d_in[1];
  const float* W1      = (const float*)d_in[2];
  const float* b1      = (const float*)d_in[3];
  const float* gamma   = (const float*)d_in[4];
  const float* beta    = (const float*)d_in[5];
  const float* bmean   = (const float*)d_in[6];
  const float* bvar    = (const float*)d_in[7];
  const float* W2      = (const float*)d_in[8];
  const float* b2      = (const float*)d_in[9];
  float* out = (float*)d_out;

  // ws usage ~5.1 MB
  char* w = (char*)d_ws;
  f16* W1h   = (f16*)w;    w += (size_t)A_ * C_ * 2;         // 131,072
  f16* W2h   = (f16*)w;    w += (size_t)C_ * A_ * 2;         // 131,072
  float* mg  = (float*)w;  w += (size_t)N_ * C_ * 4;         // 32,768
  float* sg  = (float*)w;  w += (size_t)N_ * C_ * 4;         // 32,768
  float* dba = (float*)w;  w += (size_t)N_ * A_ * 4;         // 8,192
  float* scale = (float*)w; w += 512;
  float* shift = (float*)w; w += 512;
  float* pm  = (float*)w;  w += (size_t)N_ * LT_ * C_ * 4;   // 1,572,864
  float* ps  = (float*)w;  w += (size_t)N_ * LT_ * C_ * 4;
  float* pt  = (float*)w;

  k_stats<<<dim3(N_ * C_), 256, 0, stream>>>(x, lengths, mg, sg);
  k_prep <<<dim3(N_), 256, 0, stream>>>(W1, b1, gamma, beta, bmean, bvar, W2,
                                        mg, sg, dba, scale, shift, W1h, W2h);
  k_mega <<<dim3(LT_, N_), 256, 0, stream>>>(x, W1h, W2h, dba, scale, shift,
                                             b2, lengths, pm, ps, pt);
  k_comb <<<dim3(32), 256, 0, stream>>>(pm, ps, pt, out);
}